// Round 11
// baseline (91.553 us; speedup 1.0000x reference)
//
#include <hip/hip_runtime.h>

#define SEQd 64
#define BATCHd 256
#define DF 40

typedef float f2 __attribute__((ext_vector_type(2)));
typedef __fp16 h2v __attribute__((ext_vector_type(2)));

// ---------------------------------------------------------------------------
// 8-qubit statevector: 8 lanes/circuit, 32 amps (f2) per lane, 8 circuits/wave.
// Amp index p (8 bits, wire j <-> bit 7-j): lam = p & 7 (lane), k = p >> 3 (reg).
// Gate masks/sign-rows: the verified GF(2) schedule (unchanged constants).
// Register-allocator note (R8/R9/R10 evidence): the allocator's occupancy
// target follows the LDS residency ceiling. Kernels holding the 64-VGPR state
// need >=~32KB LDS/block (or an explicit waves_per_eu cap) or the state gets
// AGPR/scratch-spilled (R8: 38MB scratch; R9/R10: ~2x VALU from AGPR moves).
// ---------------------------------------------------------------------------

template<int LM>
__device__ __forceinline__ float xch1(float v) {
  if constexpr (LM == 0) {
    return v;
  } else if constexpr (LM == 1 || LM == 2 || LM == 3 || LM == 7) {
    constexpr int ctrl = (LM == 1) ? 0xB1 : (LM == 2) ? 0x4E : (LM == 3) ? 0x1B
                       : 0x141;   // 7 = row_half_mirror (xor7 within 8 lanes)
    return __int_as_float(__builtin_amdgcn_mov_dpp(__float_as_int(v), ctrl, 0xF, 0xF, true));
  } else {  // 4,5,6 -> ds_swizzle BitMode xor
    return __int_as_float(__builtin_amdgcn_ds_swizzle(__float_as_int(v), (LM << 10) | 0x1F));
  }
}

template<int LM>
__device__ __forceinline__ f2 xch2(f2 v) {
  if constexpr (LM == 0) return v;
  f2 r; r.x = xch1<LM>(v.x); r.y = xch1<LM>(v.y); return r;
}

__device__ __forceinline__ f2 ff(f2 x, f2 y, f2 z) { return __builtin_elementwise_fma(x, y, z); }
__device__ __forceinline__ f2 cmul(f2 a, f2 b) {
  f2 r; r.x = a.x * b.x - a.y * b.y; r.y = a.x * b.y + a.y * b.x; return r;
}
__device__ __forceinline__ f2 uget(float4 f, bool bit) {
  f2 r; r.x = bit ? f.z : f.x; r.y = bit ? -f.w : f.y; return r;
}

// RY: new = c*A + (parity(p&SM)? s : -s) * partner(p^M)
template<int M, int SM>
__device__ __forceinline__ void ry32(f2* a, f2 cs, int lam) {
  constexpr int LM = M & 7, RM = M >> 3, SL = SM & 7, SR = SM >> 3;
  float t0;
  if constexpr (SL != 0) t0 = (__popc(lam & SL) & 1) ? cs.y : -cs.y;
  else                   t0 = -cs.y;
  const f2 cv = {cs.x, cs.x};
  const f2 tp = {t0, t0}, tn = {-t0, -t0};
#pragma unroll
  for (int k = 0; k < 32; ++k) {
    const int kp = k ^ RM;
    if (kp < k) continue;
    if (kp == k) {
      const f2 b = xch2<LM>(a[k]);
      a[k] = ff(b, (__builtin_popcount(k & SR) & 1) ? tn : tp, a[k] * cv);
    } else {
      const f2 b0 = xch2<LM>(a[kp]);
      const f2 b1 = xch2<LM>(a[k]);
      const f2 t_k  = (__builtin_popcount(k  & SR) & 1) ? tn : tp;
      const f2 t_kp = (__builtin_popcount(kp & SR) & 1) ? tn : tp;
      a[k]  = ff(b0, t_k,  a[k]  * cv);
      a[kp] = ff(b1, t_kp, a[kp] * cv);
    }
  }
}

// Fused U = RY(ty)*RX(tx), q=(a,b,c2,d)=(cy*cx, sy*sx, sy*cx, cy*sx).
template<int M, int SM>
__device__ __forceinline__ void su2_32(f2* a, float4 q, int lam) {
  constexpr int LM = M & 7, RM = M >> 3, SL = SM & 7, SR = SM >> 3;
  float sb, sc;
  if constexpr (SL != 0) {
    const bool p = (__popc(lam & SL) & 1) != 0;
    sb = p ? -q.y : q.y; sc = p ? -q.z : q.z;
  } else { sb = q.y; sc = q.z; }
  const f2 vqa = {q.x, q.x};
  const f2 vqw = {q.w, -q.w};
  const f2 vfc0 = {-sc, -sc}, vfb0 = {-sb, sb};
  const f2 vfc1 = { sc,  sc}, vfb1 = { sb, -sb};
#pragma unroll
  for (int k = 0; k < 32; ++k) {
    const int kp = k ^ RM;
    if (kp < k) continue;
    if (kp == k) {
      const f2 B = xch2<LM>(a[k]);
      const bool pk = (__builtin_popcount(k & SR) & 1) != 0;
      const f2 A = a[k];
      f2 r = A * vqa;
      r = ff(B, pk ? vfc1 : vfc0, r);
      r = ff(A.yx, pk ? vfb1 : vfb0, r);
      r = ff(B.yx, vqw, r);
      a[k] = r;
    } else {
      const f2 B0 = xch2<LM>(a[kp]);
      const f2 B1 = xch2<LM>(a[k]);
      const bool pk0 = (__builtin_popcount(k  & SR) & 1) != 0;
      const bool pk1 = (__builtin_popcount(kp & SR) & 1) != 0;
      const f2 A0 = a[k], A1 = a[kp];
      f2 r0 = A0 * vqa;
      r0 = ff(B0, pk0 ? vfc1 : vfc0, r0);
      r0 = ff(A0.yx, pk0 ? vfb1 : vfb0, r0);
      r0 = ff(B0.yx, vqw, r0);
      a[k] = r0;
      f2 r1 = A1 * vqa;
      r1 = ff(B1, pk1 ? vfc1 : vfc0, r1);
      r1 = ff(A1.yx, pk1 ? vfb1 : vfb0, r1);
      r1 = ff(B1.yx, vqw, r1);
      a[kp] = r1;
    }
  }
}

// 3 x [ring CNOT (free GF(2) relabeling) + 8 RY]; same verified constants.
template<typename CPtr>
__device__ __forceinline__ void layers32(f2* a, CPtr L, int lam) {
  ry32<0xC0,0x7F>(a, L[0],  lam);
  ry32<0x60,0xC0>(a, L[1],  lam);
  ry32<0x30,0xE0>(a, L[2],  lam);
  ry32<0x18,0xF0>(a, L[3],  lam);
  ry32<0x0C,0xF8>(a, L[4],  lam);
  ry32<0x06,0xFC>(a, L[5],  lam);
  ry32<0x03,0xFE>(a, L[6],  lam);
  ry32<0xC1,0xFF>(a, L[7],  lam);
  ry32<0xA0,0xD5>(a, L[8],  lam);
  ry32<0x50,0xBF>(a, L[9],  lam);
  ry32<0x28,0x5F>(a, L[10], lam);
  ry32<0x14,0xAF>(a, L[11], lam);
  ry32<0x0A,0x57>(a, L[12], lam);
  ry32<0x05,0xAB>(a, L[13], lam);
  ry32<0xC2,0x55>(a, L[14], lam);
  ry32<0x61,0xAA>(a, L[15], lam);
  ry32<0xF0,0x4C>(a, L[16], lam);
  ry32<0x78,0x6A>(a, L[17], lam);
  ry32<0x3C,0x35>(a, L[18], lam);
  ry32<0x1E,0x9A>(a, L[19], lam);
  ry32<0x0F,0xCD>(a, L[20], lam);
  ry32<0xC7,0x66>(a, L[21], lam);
  ry32<0xA3,0x33>(a, L[22], lam);
  ry32<0x91,0x99>(a, L[23], lam);
}

// initial fused RX*RY on all 8 wires (variational halves; F0 = I)
template<typename FPtr>
__device__ __forceinline__ void initial32(f2* a, FPtr F, int lam) {
  su2_32<0x80,0x80>(a, F[0], lam);
  su2_32<0x40,0x40>(a, F[1], lam);
  su2_32<0x20,0x20>(a, F[2], lam);
  su2_32<0x10,0x10>(a, F[3], lam);
  su2_32<0x08,0x08>(a, F[4], lam);
  su2_32<0x04,0x04>(a, F[5], lam);
  su2_32<0x02,0x02>(a, F[6], lam);
  su2_32<0x01,0x01>(a, F[7], lam);
}

// Encoding half from |0..0>: product state, zero exchanges.
__device__ __forceinline__ void pinit32(f2* a, const float4* F, int lam) {
  f2 c = {1.f, 0.f};
#pragma unroll
  for (int i = 0; i < 3; ++i)
    c = cmul(c, uget(F[7 - i], ((lam >> i) & 1) != 0));
  f2 wlo[4], whi[8];
#pragma unroll
  for (int t = 0; t < 4; ++t)
    wlo[t] = cmul(uget(F[4], (t & 1) != 0), uget(F[3], ((t >> 1) & 1) != 0));
#pragma unroll
  for (int t = 0; t < 8; ++t)
    whi[t] = cmul(cmul(uget(F[2], (t & 1) != 0), uget(F[1], ((t >> 1) & 1) != 0)),
                  uget(F[0], ((t >> 2) & 1) != 0));
#pragma unroll
  for (int k = 0; k < 32; ++k)
    a[k] = cmul(cmul(c, wlo[k & 3]), whi[k >> 2]);
}

__device__ __forceinline__ uint32_t packh(f2 v) {
  h2v h = __builtin_amdgcn_cvt_pkrtz(v.x, v.y);
  return __builtin_bit_cast(uint32_t, h);
}
__device__ __forceinline__ f2 unpackh(uint32_t u) {
  h2v h = __builtin_bit_cast(h2v, u);
  f2 r; r.x = (float)h[0]; r.y = (float)h[1]; return r;
}

// F3 target address for the snapshot relabel reset (value at slot p -> F3*p)
__device__ __forceinline__ int snap_tgt_lane(int lam) {
  int tgt = 0;
  if (lam & 1) tgt ^= 0x2B;
  if (lam & 2) tgt ^= 0x56;
  if (lam & 4) tgt ^= 0xAC;
  return tgt;
}
__device__ __forceinline__ int snap_rck(int k) {
  return ((k & 1) ? 0xD9 : 0) ^ ((k & 2) ? 0x33 : 0) ^ ((k & 4) ? 0x66 : 0)
       ^ ((k & 8) ? 0xCC : 0) ^ ((k & 16) ? 0x19 : 0);
}

// split-path snapshot: per-circuit 256 words, word = (q&7)*32 + (q>>3)
__device__ __forceinline__ void snap_write_g(const f2* a, uint32_t* sn, int lam) {
  const int tgt = snap_tgt_lane(lam);
#pragma unroll
  for (int k = 0; k < 32; ++k) {
    const int qq = tgt ^ snap_rck(k);
    sn[(qq & 7) * 32 + (qq >> 3)] = packh(a[k]);
  }
}

// mono-path snapshot (stride 36, as in the proven 77us kernel)
__device__ __forceinline__ void snap_write_m(const f2* a, uint32_t* sn, int lam) {
  const int tgt = snap_tgt_lane(lam);
#pragma unroll
  for (int k = 0; k < 32; ++k) {
    const int qq = tgt ^ snap_rck(k);
    sn[(qq & 7) * 36 + (qq >> 3)] = packh(a[k]);
  }
}
__device__ __forceinline__ void snap_read_m(f2* a, const uint32_t* sn, int lam) {
  const uint4* p = (const uint4*)(sn + lam * 36);
#pragma unroll
  for (int t = 0; t < 8; ++t) {
    const uint4 w = p[t];
    a[4*t+0] = unpackh(w.x); a[4*t+1] = unpackh(w.y);
    a[4*t+2] = unpackh(w.z); a[4*t+3] = unpackh(w.w);
  }
}

// <Z...>: Z0 -> SM 0x4C; Zall -> SM 0x88 (F3 rows; unchanged constants)
template<int SM>
__device__ __forceinline__ float expect32(const f2* a, int lam) {
  constexpr int SL = SM & 7, SR = SM >> 3;
  float s0 = 0.f, s1 = 0.f;
#pragma unroll
  for (int k = 0; k < 32; ++k) {
    const float p = a[k].x * a[k].x + a[k].y * a[k].y;
    if ((__builtin_popcount(k & SR) & 1) != 0) s1 += p; else s0 += p;
  }
  const float d = s0 - s1;
  float v;
  if constexpr (SL != 0) v = (__popc(lam & SL) & 1) ? -d : d;
  else                   v = d;
  v += xch1<1>(v); v += xch1<2>(v); v += xch1<4>(v);
  return v;
}

// fill one wave's 8 enc coef tables (wave-private; lgkmcnt orders LDS ops)
__device__ __forceinline__ void fill_etab(float (*et)[84], const float* __restrict__ x,
                                          int bbase, int s, int lane) {
  for (int t = lane; t < 320; t += 64) {
    const int cc = t / 40, idx = t - cc * 40;
    const float ang = x[((size_t)(bbase + cc) * 64 + s) * 40 + idx];
    float sn, cn; __sincosf(ang * 0.5f, &sn, &cn);
    if (idx < 16) {
      const int wire = idx >> 1, isy = idx & 1;
      et[cc][wire * 4 + isy * 2 + 0] = cn;
      et[cc][wire * 4 + isy * 2 + 1] = sn;
    } else {
      et[cc][32 + (idx - 16) * 2 + 0] = cn;
      et[cc][32 + (idx - 16) * 2 + 1] = sn;
    }
  }
  {  // fold (cx,sx,cy,sy) -> (a,b,c2,d): 8 circuits x 8 wires = 64 lanes
    const int cc = lane >> 3, wire = lane & 7;
    float4* qt = (float4*)et[cc];
    const float4 f = qt[wire];
    qt[wire] = make_float4(f.z * f.x, f.w * f.y, f.w * f.x, f.z * f.y);
  }
}

// per-(s,half) variational coefficient tables: 80 floats = 8*float4 + 24*float2
__global__ __launch_bounds__(256) void prep_var(
    const float* __restrict__ pQ, const float* __restrict__ pK,
    const float* __restrict__ pV, float* __restrict__ vtab)
{
  const int t = blockIdx.x * 256 + threadIdx.x;
  if (t >= SEQd * 3 * 32) return;
  const int slot = t & 31;
  const int sh = t >> 5;
  const int h = sh % 3, sp = sh / 3;
  const float* w = ((h == 0) ? pQ : (h == 1) ? pK : pV) + sp * DF;
  float* o = vtab + sh * 80;
  if (slot < 8) {
    float cx, sx, cy, sy;
    __sincosf(w[2 * slot]     * 0.5f, &sx, &cx);
    __sincosf(w[2 * slot + 1] * 0.5f, &sy, &cy);
    ((float4*)o)[slot] = make_float4(cy * cx, sy * sx, sy * cx, cy * sx);
  } else {
    float sn, cn;
    __sincosf(w[16 + (slot - 8)] * 0.5f, &sn, &cn);
    ((float2*)(o + 32))[slot - 8] = make_float2(cn, sn);
  }
}

// === Kernel A: encoding halves -> fp16 snapshot in global (coalesced) ======
// (LDS = 43.5KB -> 3 blocks/CU ceiling -> allocator keeps state in VGPRs.)
__global__ __launch_bounds__(256, 3) void qsal_enc(
    const float* __restrict__ x, uint32_t* __restrict__ snapg)
{
  __shared__ __align__(16) float etab[4][8][84];
  __shared__ __align__(16) uint32_t snap[4][8][264];
  const int tid = threadIdx.x;
  const int wid = tid >> 6, lane = tid & 63;
  const int lam = lane & 7, cig = lane >> 3;
  const int cgrp = blockIdx.x * 4 + wid;
  const int s = cgrp & 63;
  const int bbase = (cgrp >> 6) << 3;

  fill_etab(etab[wid], x, bbase, s, lane);

  f2 st[32];
  pinit32(st, (const float4*)etab[wid][cig], lam);
  layers32(st, (const f2*)(etab[wid][cig] + 32), lam);
  snap_write_g(st, snap[wid][cig], lam);

  // LDS -> global, coalesced: each circuit's 256 words are q-linear
  uint32_t* gb = snapg + ((size_t)cgrp * 8 + cig) * 256;
#pragma unroll
  for (int r = 0; r < 8; ++r) {
    const int u4 = lam + 8 * r;                       // uint4 idx 0..63
    const uint4 v = *(const uint4*)&snap[wid][cig][u4 * 4];
    ((uint4*)gb)[u4] = v;
  }
}

// === Kernel B: one variational half per wave (3 waves/block, no barriers) ==
// ltab deliberately 32KB: drops the LDS residency ceiling to 5 blocks/CU so
// the allocator's occupancy target is ~4 waves/SIMD -> VGPR budget >=128 ->
// the 64-reg state stays in arch VGPRs (R9/R10: 56-60 VGPR = AGPR-spill, 2x
// VALU). Plus explicit waves_per_eu range as the documented knob.
__global__ __launch_bounds__(192)
__attribute__((amdgpu_waves_per_eu(3, 4)))
void qsal_var(
    const uint32_t* __restrict__ snapg, const float* __restrict__ vtab,
    float* __restrict__ Qo, float* __restrict__ Ko, float* __restrict__ Vo)
{
  __shared__ __align__(16) float ltab[3][2720];      // use first 80/row; 32KB total
  const int tid = threadIdx.x;
  const int h = tid / 64, lane = tid & 63;           // h = wave id = half
  const int lam = lane & 7, cig = lane >> 3;
  const int cgrp = blockIdx.x;
  const int s = cgrp & 63;
  const int bbase = (cgrp >> 6) << 3;

  if (lane < 20)
    ((float4*)ltab[h])[lane] = ((const float4*)(vtab + s * 240 + h * 80))[lane];

  f2 st[32];
  const uint4* sp = (const uint4*)(snapg + (((size_t)cgrp * 8 + cig) * 256 + lam * 32));
#pragma unroll
  for (int t = 0; t < 8; ++t) {
    const uint4 w = sp[t];
    st[4*t+0] = unpackh(w.x); st[4*t+1] = unpackh(w.y);
    st[4*t+2] = unpackh(w.z); st[4*t+3] = unpackh(w.w);
  }
  initial32(st, (const float4*)ltab[h], lam);
  layers32(st, (const f2*)(ltab[h] + 32), lam);
  const float e = (h == 2) ? expect32<0x88>(st, lam) : expect32<0x4C>(st, lam);
  if (lam == 0) {
    float* op = (h == 0) ? Qo : (h == 1) ? Ko : Vo;
    op[(bbase + cig) * 64 + s] = e;
  }
}

// === Fallback: the proven 77us monolithic kernel (ws too small for split) ==
__global__ __launch_bounds__(256, 3) void qsal_mono(
    const float* __restrict__ x, const float* __restrict__ vtab,
    float* __restrict__ Qo, float* __restrict__ Ko, float* __restrict__ Vo)
{
  __shared__ __align__(16) float etab[32][84];
  __shared__ __align__(16) uint32_t snap[32][296];
  __shared__ __align__(16) float vtabs[240];
  const int tid = threadIdx.x;
  const int wid = tid >> 6, lane = tid & 63;
  const int lam = lane & 7;
  const int cig = (wid << 3) | (lane >> 3);
  const int s = blockIdx.x & 63;
  const int bbase = (blockIdx.x >> 6) << 5;

  for (int t = tid; t < 1280; t += 256) {
    const int cc = t / 40, idx = t - cc * 40;
    const float ang = x[((size_t)(bbase + cc) * 64 + s) * 40 + idx];
    float sn, cn; __sincosf(ang * 0.5f, &sn, &cn);
    if (idx < 16) {
      const int wire = idx >> 1, isy = idx & 1;
      etab[cc][wire * 4 + isy * 2 + 0] = cn;
      etab[cc][wire * 4 + isy * 2 + 1] = sn;
    } else {
      etab[cc][32 + (idx - 16) * 2 + 0] = cn;
      etab[cc][32 + (idx - 16) * 2 + 1] = sn;
    }
  }
  if (tid < 60) ((float4*)vtabs)[tid] = ((const float4*)(vtab + s * 240))[tid];
  __syncthreads();
  {
    const int cc = tid >> 3, wire = tid & 7;
    float4* qt = (float4*)etab[cc];
    const float4 f = qt[wire];
    qt[wire] = make_float4(f.z * f.x, f.w * f.y, f.w * f.x, f.z * f.y);
  }
  __syncthreads();

  f2 st[32];
#pragma unroll 1
  for (int ph = 0; ph < 4; ++ph) {
    const f2* L;
    if (ph == 0) {
      pinit32(st, (const float4*)etab[cig], lam);
      L = (const f2*)(etab[cig] + 32);
    } else {
      snap_read_m(st, snap[cig], lam);
      const float* th = vtabs + (ph - 1) * 80;
      initial32(st, (const float4*)th, lam);
      L = (const f2*)(th + 32);
    }
    layers32(st, L, lam);
    if (ph == 0) {
      snap_write_m(st, snap[cig], lam);
    } else {
      const float e = (ph == 3) ? expect32<0x88>(st, lam) : expect32<0x4C>(st, lam);
      if (lam == 0) {
        float* op = (ph == 1) ? Qo : (ph == 2) ? Ko : Vo;
        op[(bbase + cig) * 64 + s] = e;
      }
    }
    __syncthreads();
  }
}

__global__ __launch_bounds__(256) void qsal_attn(
    const float* __restrict__ x,
    const float* __restrict__ Qv,
    const float* __restrict__ Kv,
    const float* __restrict__ Vv,
    float* __restrict__ out)
{
  const int tid  = threadIdx.x;
  const int wid  = tid >> 6;
  const int lane = tid & 63;                 // m
  const int bi   = blockIdx.x * 4 + wid;     // b*64 + i
  const int b    = bi >> 6;

  const float q = Qv[bi];
  const float k = Kv[b * 64 + lane];
  const float v = Vv[b * 64 + lane];
  const float d = q - k;
  float e  = __expf(-d * d);
  float ev = e * v;
#pragma unroll
  for (int m = 1; m < 64; m <<= 1) {
    e  += __shfl_xor(e,  m, 64);
    ev += __shfl_xor(ev, m, 64);
  }
  const float att = ev / e;

  const size_t row = (size_t)bi * DF;
  if (lane < DF) out[row + lane] = x[row + lane] + att;
}

extern "C" void kernel_launch(void* const* d_in, const int* in_sizes, int n_in,
                              void* d_out, int out_size, void* d_ws, size_t ws_size,
                              hipStream_t stream) {
  const float* x  = (const float*)d_in[0];
  const float* pQ = (const float*)d_in[1];
  const float* pK = (const float*)d_in[2];
  const float* pV = (const float*)d_in[3];
  float* out = (float*)d_out;

  const int NC = BATCHd * SEQd;                  // 16384 circuits
  float* Qv   = (float*)d_ws;                    // [16384]
  float* Kv   = Qv + NC;
  float* Vv   = Kv + NC;
  float* vtab = Vv + NC;                         // [64*3*80] = 15360
  uint32_t* snapg = (uint32_t*)(vtab + SEQd * 3 * 80);   // [16384*256] u32 = 16 MB

  const size_t need = (size_t)(3 * NC + SEQd * 3 * 80) * 4 + (size_t)NC * 256 * 4;

  prep_var<<<dim3(24), dim3(256), 0, stream>>>(pQ, pK, pV, vtab);
  if (ws_size >= need) {
    qsal_enc<<<dim3(512), dim3(256), 0, stream>>>(x, snapg);
    qsal_var<<<dim3(2048), dim3(192), 0, stream>>>(snapg, vtab, Qv, Kv, Vv);
  } else {
    qsal_mono<<<dim3(512), dim3(256), 0, stream>>>(x, vtab, Qv, Kv, Vv);
  }
  qsal_attn<<<dim3(NC / 4), dim3(256), 0, stream>>>(x, Qv, Kv, Vv, out);
}

// Round 12
// 77.899 us; speedup vs baseline: 1.1753x; 1.1753x over previous
//
#include <hip/hip_runtime.h>

#define SEQd 64
#define BATCHd 256
#define DF 40

typedef float f2 __attribute__((ext_vector_type(2)));
typedef __fp16 h2v __attribute__((ext_vector_type(2)));

// ---------------------------------------------------------------------------
// 8-qubit statevector: 8 lanes/circuit, 32 amps per lane, 8 circuits/wave.
// Amp k (8 bits, wire j <-> bit 7-j): lam = p & 7 (lane), k = p >> 3 (reg).
// NEW this round: SoA register layout — rr[16], ii[16] f2 pairs, amp k lives
// at (rr[k>>1][k&1], ii[k>>1][k&1]) — with gate math as explicit inline-asm
// v_pk_fma_f32 / v_pk_mul_f32 (VOP3P). hipcc scalarizes f2 vector math
// (measured: ~2.2-2.9x VALU inflation vs pk-instruction count in R7-R11);
// SoA+asm halves VALU issue. Intra-pair partner swap (RM&1) = op_sel
// modifier; per-half sign = neg_lo/neg_hi modifier; complex J() needs no
// swizzle in SoA. Masks/sign-rows: the verified GF(2) schedule, unchanged.
// ---------------------------------------------------------------------------

__device__ __forceinline__ f2 mkf2(float a, float b) { f2 r; r.x = a; r.y = b; return r; }

template<int LM>
__device__ __forceinline__ float xch1(float v) {
  if constexpr (LM == 0) {
    return v;
  } else if constexpr (LM == 1 || LM == 2 || LM == 3 || LM == 7) {
    constexpr int ctrl = (LM == 1) ? 0xB1 : (LM == 2) ? 0x4E : (LM == 3) ? 0x1B
                       : 0x141;   // 7 = row_half_mirror (xor7 within 8 lanes)
    return __int_as_float(__builtin_amdgcn_mov_dpp(__float_as_int(v), ctrl, 0xF, 0xF, true));
  } else {  // 4,5,6 -> ds_swizzle BitMode xor
    return __int_as_float(__builtin_amdgcn_ds_swizzle(__float_as_int(v), (LM << 10) | 0x1F));
  }
}

template<int LM>
__device__ __forceinline__ f2 xch2(f2 v) {
  if constexpr (LM == 0) return v;
  f2 r; r.x = xch1<LM>(v.x); r.y = xch1<LM>(v.y); return r;
}

// ---- packed-f32 asm primitives -------------------------------------------
__device__ __forceinline__ f2 pkmul(f2 a, f2 b) {
  f2 d;
  asm("v_pk_mul_f32 %0, %1, %2" : "=v"(d) : "v"(a), "v"(b));
  return d;
}
// d = (SWAPA? swap_halves(a) : a) * (NEGB? -b : b) + c
template<bool NEGB, bool SWAPA>
__device__ __forceinline__ f2 pkfma(f2 a, f2 b, f2 c) {
  f2 d;
  if constexpr (!NEGB && !SWAPA)
    asm("v_pk_fma_f32 %0, %1, %2, %3" : "=v"(d) : "v"(a), "v"(b), "v"(c));
  else if constexpr (NEGB && !SWAPA)
    asm("v_pk_fma_f32 %0, %1, %2, %3 neg_lo:[0,1,0] neg_hi:[0,1,0]"
        : "=v"(d) : "v"(a), "v"(b), "v"(c));
  else if constexpr (!NEGB && SWAPA)
    asm("v_pk_fma_f32 %0, %1, %2, %3 op_sel:[1,0,0] op_sel_hi:[0,1,1]"
        : "=v"(d) : "v"(a), "v"(b), "v"(c));
  else
    asm("v_pk_fma_f32 %0, %1, %2, %3 op_sel:[1,0,0] op_sel_hi:[0,1,1] neg_lo:[0,1,0] neg_hi:[0,1,0]"
        : "=v"(d) : "v"(a), "v"(b), "v"(c));
  return d;
}

__device__ __forceinline__ f2 cmul(f2 a, f2 b) {
  f2 r; r.x = a.x * b.x - a.y * b.y; r.y = a.x * b.y + a.y * b.x; return r;
}
__device__ __forceinline__ f2 uget(float4 f, bool bit) {
  f2 r; r.x = bit ? f.z : f.x; r.y = bit ? -f.w : f.y; return r;
}

// ---- RY gate (SoA, recursive over dest pair J) ---------------------------
// amp-level semantics (verified R10): a[k] = c*a[k] + t(k)*b[k],
// t(k) = parity(k&SR) ? -t0 : +t0, b[k] = xch(a[k^RM]).
template<int M, int SM, int J>
__device__ __forceinline__ void ry_rec(f2* rr, f2* ii, f2 CC, f2 TV) {
  if constexpr (J < 16) {
    constexpr int LM = M & 7, RM = M >> 3;
    constexpr int RJ = RM >> 1;
    constexpr bool R0 = (RM & 1) != 0;
    constexpr int JP = J ^ RJ;
    if constexpr (JP >= J) {
      constexpr int SRj = (SM >> 3) >> 1;
      constexpr bool PJ = (__builtin_popcount(J & SRj) & 1) != 0;
      if constexpr (JP == J) {
        const f2 br = xch2<LM>(rr[J]);
        const f2 bi = xch2<LM>(ii[J]);
        rr[J] = pkfma<PJ, R0>(br, TV, pkmul(rr[J], CC));
        ii[J] = pkfma<PJ, R0>(bi, TV, pkmul(ii[J], CC));
      } else {
        constexpr bool PJP = (__builtin_popcount(JP & SRj) & 1) != 0;
        const f2 br0 = xch2<LM>(rr[JP]);
        const f2 bi0 = xch2<LM>(ii[JP]);
        const f2 br1 = xch2<LM>(rr[J]);
        const f2 bi1 = xch2<LM>(ii[J]);
        rr[J]  = pkfma<PJ,  R0>(br0, TV, pkmul(rr[J],  CC));
        ii[J]  = pkfma<PJ,  R0>(bi0, TV, pkmul(ii[J],  CC));
        rr[JP] = pkfma<PJP, R0>(br1, TV, pkmul(rr[JP], CC));
        ii[JP] = pkfma<PJP, R0>(bi1, TV, pkmul(ii[JP], CC));
      }
    }
    ry_rec<M, SM, J + 1>(rr, ii, CC, TV);
  }
}

template<int M, int SM>
__device__ __forceinline__ void ry32s(f2* rr, f2* ii, f2 cs, int lam) {
  constexpr int SL = SM & 7;
  constexpr bool S0v = ((SM >> 3) & 1) != 0;
  float t0;
  if constexpr (SL != 0) t0 = (__popc(lam & SL) & 1) ? cs.y : -cs.y;
  else                   t0 = -cs.y;
  const f2 CC = mkf2(cs.x, cs.x);
  const f2 TV = mkf2(t0, S0v ? -t0 : t0);
  ry_rec<M, SM, 0>(rr, ii, CC, TV);
}

// ---- fused SU2 = RY*RX gate (SoA) ----------------------------------------
// amp-level (verified R10, pk = parity(k&SR)):
//  re' = qx*re + c(k)*bre + d(k)*im + qw*bim     c(k)=pk? +sc:-sc
//  im' = qx*im + c(k)*bim + e(k)*re - qw*bre     d(k)=pk? +sb:-sb, e(k)=-d(k)
template<int M, int SM, int J>
__device__ __forceinline__ void su2_rec(f2* rr, f2* ii, f2 QX, f2 QW, f2 SC, f2 SB) {
  if constexpr (J < 16) {
    constexpr int LM = M & 7, RM = M >> 3;
    constexpr int RJ = RM >> 1;
    constexpr bool R0 = (RM & 1) != 0;
    constexpr int JP = J ^ RJ;
    if constexpr (JP >= J) {
      constexpr int SRj = (SM >> 3) >> 1;
      constexpr bool PJ = (__builtin_popcount(J & SRj) & 1) != 0;
      if constexpr (JP == J) {
        const f2 br = xch2<LM>(rr[J]);
        const f2 bi = xch2<LM>(ii[J]);
        f2 t = pkmul(rr[J], QX);
        t = pkfma<!PJ, R0>(br, SC, t);
        t = pkfma<!PJ, false>(ii[J], SB, t);
        t = pkfma<false, R0>(bi, QW, t);
        f2 u = pkmul(ii[J], QX);
        u = pkfma<!PJ, R0>(bi, SC, u);
        u = pkfma<PJ, false>(rr[J], SB, u);
        u = pkfma<true, R0>(br, QW, u);
        rr[J] = t; ii[J] = u;
      } else {
        constexpr bool PJP = (__builtin_popcount(JP & SRj) & 1) != 0;
        const f2 br0 = xch2<LM>(rr[JP]);
        const f2 bi0 = xch2<LM>(ii[JP]);
        const f2 br1 = xch2<LM>(rr[J]);
        const f2 bi1 = xch2<LM>(ii[J]);
        f2 t0v = pkmul(rr[J], QX);
        t0v = pkfma<!PJ, R0>(br0, SC, t0v);
        t0v = pkfma<!PJ, false>(ii[J], SB, t0v);
        t0v = pkfma<false, R0>(bi0, QW, t0v);
        f2 u0v = pkmul(ii[J], QX);
        u0v = pkfma<!PJ, R0>(bi0, SC, u0v);
        u0v = pkfma<PJ, false>(rr[J], SB, u0v);
        u0v = pkfma<true, R0>(br0, QW, u0v);
        f2 t1v = pkmul(rr[JP], QX);
        t1v = pkfma<!PJP, R0>(br1, SC, t1v);
        t1v = pkfma<!PJP, false>(ii[JP], SB, t1v);
        t1v = pkfma<false, R0>(bi1, QW, t1v);
        f2 u1v = pkmul(ii[JP], QX);
        u1v = pkfma<!PJP, R0>(bi1, SC, u1v);
        u1v = pkfma<PJP, false>(rr[JP], SB, u1v);
        u1v = pkfma<true, R0>(br1, QW, u1v);
        rr[J] = t0v; ii[J] = u0v; rr[JP] = t1v; ii[JP] = u1v;
      }
    }
    su2_rec<M, SM, J + 1>(rr, ii, QX, QW, SC, SB);
  }
}

template<int M, int SM>
__device__ __forceinline__ void su2g(f2* rr, f2* ii, float4 q, int lam) {
  constexpr int SL = SM & 7;
  constexpr bool S0v = ((SM >> 3) & 1) != 0;
  float sb, sc;
  if constexpr (SL != 0) {
    const bool p = (__popc(lam & SL) & 1) != 0;
    sb = p ? -q.y : q.y; sc = p ? -q.z : q.z;
  } else { sb = q.y; sc = q.z; }
  const f2 QX = mkf2(q.x, q.x), QW = mkf2(q.w, q.w);
  const f2 SCv = mkf2(sc, S0v ? -sc : sc);
  const f2 SBv = mkf2(sb, S0v ? -sb : sb);
  su2_rec<M, SM, 0>(rr, ii, QX, QW, SCv, SBv);
}

// 3 x [ring CNOT (free GF(2) relabeling) + 8 RY]; verified constants.
__device__ __forceinline__ void layers32s(f2* rr, f2* ii, const f2* L, int lam) {
  ry32s<0xC0,0x7F>(rr, ii, L[0],  lam);
  ry32s<0x60,0xC0>(rr, ii, L[1],  lam);
  ry32s<0x30,0xE0>(rr, ii, L[2],  lam);
  ry32s<0x18,0xF0>(rr, ii, L[3],  lam);
  ry32s<0x0C,0xF8>(rr, ii, L[4],  lam);
  ry32s<0x06,0xFC>(rr, ii, L[5],  lam);
  ry32s<0x03,0xFE>(rr, ii, L[6],  lam);
  ry32s<0xC1,0xFF>(rr, ii, L[7],  lam);
  ry32s<0xA0,0xD5>(rr, ii, L[8],  lam);
  ry32s<0x50,0xBF>(rr, ii, L[9],  lam);
  ry32s<0x28,0x5F>(rr, ii, L[10], lam);
  ry32s<0x14,0xAF>(rr, ii, L[11], lam);
  ry32s<0x0A,0x57>(rr, ii, L[12], lam);
  ry32s<0x05,0xAB>(rr, ii, L[13], lam);
  ry32s<0xC2,0x55>(rr, ii, L[14], lam);
  ry32s<0x61,0xAA>(rr, ii, L[15], lam);
  ry32s<0xF0,0x4C>(rr, ii, L[16], lam);
  ry32s<0x78,0x6A>(rr, ii, L[17], lam);
  ry32s<0x3C,0x35>(rr, ii, L[18], lam);
  ry32s<0x1E,0x9A>(rr, ii, L[19], lam);
  ry32s<0x0F,0xCD>(rr, ii, L[20], lam);
  ry32s<0xC7,0x66>(rr, ii, L[21], lam);
  ry32s<0xA3,0x33>(rr, ii, L[22], lam);
  ry32s<0x91,0x99>(rr, ii, L[23], lam);
}

// initial fused RX*RY on all 8 wires (variational halves; F0 = I)
__device__ __forceinline__ void initial32s(f2* rr, f2* ii, const float4* F, int lam) {
  su2g<0x80,0x80>(rr, ii, F[0], lam);
  su2g<0x40,0x40>(rr, ii, F[1], lam);
  su2g<0x20,0x20>(rr, ii, F[2], lam);
  su2g<0x10,0x10>(rr, ii, F[3], lam);
  su2g<0x08,0x08>(rr, ii, F[4], lam);
  su2g<0x04,0x04>(rr, ii, F[5], lam);
  su2g<0x02,0x02>(rr, ii, F[6], lam);
  su2g<0x01,0x01>(rr, ii, F[7], lam);
}

// Encoding half from |0..0>: product state, zero exchanges.
__device__ __forceinline__ void pinit32s(f2* rr, f2* ii, const float4* F, int lam) {
  f2 c = mkf2(1.f, 0.f);
#pragma unroll
  for (int i = 0; i < 3; ++i)
    c = cmul(c, uget(F[7 - i], ((lam >> i) & 1) != 0));
  f2 wlo[4], whi[8];
#pragma unroll
  for (int t = 0; t < 4; ++t)
    wlo[t] = cmul(uget(F[4], (t & 1) != 0), uget(F[3], ((t >> 1) & 1) != 0));
#pragma unroll
  for (int t = 0; t < 8; ++t)
    whi[t] = cmul(cmul(uget(F[2], (t & 1) != 0), uget(F[1], ((t >> 1) & 1) != 0)),
                  uget(F[0], ((t >> 2) & 1) != 0));
#pragma unroll
  for (int k = 0; k < 32; ++k) {
    const f2 a = cmul(cmul(c, wlo[k & 3]), whi[k >> 2]);
    rr[k >> 1][k & 1] = a.x;
    ii[k >> 1][k & 1] = a.y;
  }
}

__device__ __forceinline__ uint32_t packh(float a, float b) {
  h2v h = __builtin_amdgcn_cvt_pkrtz(a, b);
  return __builtin_bit_cast(uint32_t, h);
}
__device__ __forceinline__ f2 unpackh(uint32_t u) {
  h2v h = __builtin_bit_cast(h2v, u);
  f2 r; r.x = (float)h[0]; r.y = (float)h[1]; return r;
}

// snapshot relabel reset: value at slot p -> address F3*p (stride-36 layout)
__device__ __forceinline__ int snap_tgt_lane(int lam) {
  int tgt = 0;
  if (lam & 1) tgt ^= 0x2B;
  if (lam & 2) tgt ^= 0x56;
  if (lam & 4) tgt ^= 0xAC;
  return tgt;
}
__device__ __forceinline__ int snap_rck(int k) {
  return ((k & 1) ? 0xD9 : 0) ^ ((k & 2) ? 0x33 : 0) ^ ((k & 4) ? 0x66 : 0)
       ^ ((k & 8) ? 0xCC : 0) ^ ((k & 16) ? 0x19 : 0);
}

__device__ __forceinline__ void snap_write_s(const f2* rr, const f2* ii, uint32_t* sn, int lam) {
  const int tgt = snap_tgt_lane(lam);
#pragma unroll
  for (int k = 0; k < 32; ++k) {
    const int qq = tgt ^ snap_rck(k);
    sn[(qq & 7) * 36 + (qq >> 3)] = packh(rr[k >> 1][k & 1], ii[k >> 1][k & 1]);
  }
}

__device__ __forceinline__ void snap_read_s(f2* rr, f2* ii, const uint32_t* sn, int lam) {
  const uint4* p = (const uint4*)(sn + lam * 36);
#pragma unroll
  for (int t = 0; t < 8; ++t) {
    const uint4 w = p[t];
    const f2 a0 = unpackh(w.x), a1 = unpackh(w.y), a2 = unpackh(w.z), a3 = unpackh(w.w);
    rr[2 * t]     = mkf2(a0.x, a1.x);  ii[2 * t]     = mkf2(a0.y, a1.y);
    rr[2 * t + 1] = mkf2(a2.x, a3.x);  ii[2 * t + 1] = mkf2(a2.y, a3.y);
  }
}

// <Z...>: Z0 -> SM 0x4C; Zall -> SM 0x88 (F3 rows; unchanged constants)
template<int SM>
__device__ __forceinline__ float expect32s(const f2* rr, const f2* ii, int lam) {
  constexpr int SL = SM & 7, SR = SM >> 3;
  constexpr int SRj = SR >> 1;
  constexpr bool S0v = (SR & 1) != 0;
  float d = 0.f;
#pragma unroll
  for (int j = 0; j < 16; ++j) {
    const f2 pp = pkfma<false, false>(ii[j], ii[j], pkmul(rr[j], rr[j]));
    float contrib;
    if constexpr (S0v) contrib = pp.x - pp.y;
    else               contrib = pp.x + pp.y;
    const bool pj = (__builtin_popcount(j & SRj) & 1) != 0;
    d += pj ? -contrib : contrib;
  }
  float v;
  if constexpr (SL != 0) v = (__popc(lam & SL) & 1) ? -d : d;
  else                   v = d;
  v += xch1<1>(v); v += xch1<2>(v); v += xch1<4>(v);
  return v;
}

// per-(s,half) variational coefficient tables: 80 floats = 8*float4 + 24*float2
__global__ __launch_bounds__(256) void prep_var(
    const float* __restrict__ pQ, const float* __restrict__ pK,
    const float* __restrict__ pV, float* __restrict__ vtab)
{
  const int t = blockIdx.x * 256 + threadIdx.x;
  if (t >= SEQd * 3 * 32) return;
  const int slot = t & 31;
  const int sh = t >> 5;
  const int h = sh % 3, sp = sh / 3;
  const float* w = ((h == 0) ? pQ : (h == 1) ? pK : pV) + sp * DF;
  float* o = vtab + sh * 80;
  if (slot < 8) {
    float cx, sx, cy, sy;
    __sincosf(w[2 * slot]     * 0.5f, &sx, &cx);
    __sincosf(w[2 * slot + 1] * 0.5f, &sy, &cy);
    ((float4*)o)[slot] = make_float4(cy * cx, sy * sx, sy * cx, cy * sx);
  } else {
    float sn, cn;
    __sincosf(w[16 + (slot - 8)] * 0.5f, &sn, &cn);
    ((float2*)(o + 32))[slot - 8] = make_float2(cn, sn);
  }
}

// Monolithic circuits kernel (proven R7 structure: 4 waves/block, rolled
// phase loop, big LDS -> VGPR-friendly allocation, bounds (256,3)).
__global__ __launch_bounds__(256, 3) void qsal_mono(
    const float* __restrict__ x, const float* __restrict__ vtab,
    float* __restrict__ Qo, float* __restrict__ Ko, float* __restrict__ Vo)
{
  __shared__ __align__(16) float etab[32][84];
  __shared__ __align__(16) uint32_t snap[32][296];
  __shared__ __align__(16) float vtabs[240];
  const int tid = threadIdx.x;
  const int wid = tid >> 6, lane = tid & 63;
  const int lam = lane & 7;
  const int cig = (wid << 3) | (lane >> 3);
  const int s = blockIdx.x & 63;
  const int bbase = (blockIdx.x >> 6) << 5;

  for (int t = tid; t < 1280; t += 256) {
    const int cc = t / 40, idx = t - cc * 40;
    const float ang = x[((size_t)(bbase + cc) * 64 + s) * 40 + idx];
    float sn, cn; __sincosf(ang * 0.5f, &sn, &cn);
    if (idx < 16) {
      const int wire = idx >> 1, isy = idx & 1;
      etab[cc][wire * 4 + isy * 2 + 0] = cn;
      etab[cc][wire * 4 + isy * 2 + 1] = sn;
    } else {
      etab[cc][32 + (idx - 16) * 2 + 0] = cn;
      etab[cc][32 + (idx - 16) * 2 + 1] = sn;
    }
  }
  if (tid < 60) ((float4*)vtabs)[tid] = ((const float4*)(vtab + s * 240))[tid];
  __syncthreads();
  {
    const int cc = tid >> 3, wire = tid & 7;
    float4* qt = (float4*)etab[cc];
    const float4 f = qt[wire];
    qt[wire] = make_float4(f.z * f.x, f.w * f.y, f.w * f.x, f.z * f.y);
  }
  __syncthreads();

  f2 rr[16], ii[16];
#pragma unroll 1
  for (int ph = 0; ph < 4; ++ph) {
    const f2* L;
    if (ph == 0) {
      pinit32s(rr, ii, (const float4*)etab[cig], lam);
      L = (const f2*)(etab[cig] + 32);
    } else {
      snap_read_s(rr, ii, snap[cig], lam);
      const float* th = vtabs + (ph - 1) * 80;
      initial32s(rr, ii, (const float4*)th, lam);
      L = (const f2*)(th + 32);
    }
    layers32s(rr, ii, L, lam);
    if (ph == 0) {
      snap_write_s(rr, ii, snap[cig], lam);
    } else {
      const float e = (ph == 3) ? expect32s<0x88>(rr, ii, lam)
                                : expect32s<0x4C>(rr, ii, lam);
      if (lam == 0) {
        float* op = (ph == 1) ? Qo : (ph == 2) ? Ko : Vo;
        op[(bbase + cig) * 64 + s] = e;
      }
    }
    __syncthreads();
  }
}

__global__ __launch_bounds__(256) void qsal_attn(
    const float* __restrict__ x,
    const float* __restrict__ Qv,
    const float* __restrict__ Kv,
    const float* __restrict__ Vv,
    float* __restrict__ out)
{
  const int tid  = threadIdx.x;
  const int wid  = tid >> 6;
  const int lane = tid & 63;                 // m
  const int bi   = blockIdx.x * 4 + wid;     // b*64 + i
  const int b    = bi >> 6;

  const float q = Qv[bi];
  const float k = Kv[b * 64 + lane];
  const float v = Vv[b * 64 + lane];
  const float d = q - k;
  float e  = __expf(-d * d);
  float ev = e * v;
#pragma unroll
  for (int m = 1; m < 64; m <<= 1) {
    e  += __shfl_xor(e,  m, 64);
    ev += __shfl_xor(ev, m, 64);
  }
  const float att = ev / e;

  const size_t row = (size_t)bi * DF;
  if (lane < DF) out[row + lane] = x[row + lane] + att;
}

extern "C" void kernel_launch(void* const* d_in, const int* in_sizes, int n_in,
                              void* d_out, int out_size, void* d_ws, size_t ws_size,
                              hipStream_t stream) {
  const float* x  = (const float*)d_in[0];
  const float* pQ = (const float*)d_in[1];
  const float* pK = (const float*)d_in[2];
  const float* pV = (const float*)d_in[3];
  float* out = (float*)d_out;

  const int NC = BATCHd * SEQd;                  // 16384 circuits
  float* Qv   = (float*)d_ws;                    // [16384]
  float* Kv   = Qv + NC;
  float* Vv   = Kv + NC;
  float* vtab = Vv + NC;                         // [64*3*80]

  prep_var<<<dim3(24), dim3(256), 0, stream>>>(pQ, pK, pV, vtab);
  qsal_mono<<<dim3(512), dim3(256), 0, stream>>>(x, vtab, Qv, Kv, Vv);
  qsal_attn<<<dim3(NC / 4), dim3(256), 0, stream>>>(x, Qv, Kv, Vv, out);
}